// Round 1
// baseline (154.280 us; speedup 1.0000x reference)
//
#include <hip/hip_runtime.h>
#include <math.h>

// ---------------------------------------------------------------------------
// Scattering transform (J=2, L=8, N=32) + GroupNorm(27) + Linear(15552->10)
// Fully fused into 3 kernels. All FFTs are per-thread, fully-unrolled
// register FFTs with compile-time twiddles (constexpr table -> literals).
// LDS is SoA (separate re/im) with +1-padded leading dims => conflict-free
// row and column passes.
// ---------------------------------------------------------------------------

// twiddle tables: C32T[k] = cos(2*pi*k/32), S32T[k] = sin(2*pi*k/32)
constexpr float C32T[32] = {
  1.0000000000f, 0.9807852804f, 0.9238795325f, 0.8314696123f,
  0.7071067812f, 0.5555702330f, 0.3826834324f, 0.1950903220f,
  0.0000000000f,-0.1950903220f,-0.3826834324f,-0.5555702330f,
 -0.7071067812f,-0.8314696123f,-0.9238795325f,-0.9807852804f,
 -1.0000000000f,-0.9807852804f,-0.9238795325f,-0.8314696123f,
 -0.7071067812f,-0.5555702330f,-0.3826834324f,-0.1950903220f,
  0.0000000000f, 0.1950903220f, 0.3826834324f, 0.5555702330f,
  0.7071067812f, 0.8314696123f, 0.9238795325f, 0.9807852804f };
constexpr float S32T[32] = {
  0.0000000000f, 0.1950903220f, 0.3826834324f, 0.5555702330f,
  0.7071067812f, 0.8314696123f, 0.9238795325f, 0.9807852804f,
  1.0000000000f, 0.9807852804f, 0.9238795325f, 0.8314696123f,
  0.7071067812f, 0.5555702330f, 0.3826834324f, 0.1950903220f,
  0.0000000000f,-0.1950903220f,-0.3826834324f,-0.5555702330f,
 -0.7071067812f,-0.8314696123f,-0.9238795325f,-0.9807852804f,
 -1.0000000000f,-0.9807852804f,-0.9238795325f,-0.8314696123f,
 -0.7071067812f,-0.5555702330f,-0.3826834324f,-0.1950903220f };

// In-register radix-2 DIT FFT, fully unrolled, compile-time twiddles.
// INV=false: X[k] = sum x[n] e^{-2pi i nk/N} (numpy fft, no scale)
// INV=true : unnormalized inverse (caller applies 1/N^2 for 2D)
template<int N, bool INV>
__device__ __forceinline__ void fft1d(float2 (&a)[N]) {
  constexpr int LOG = (N == 32) ? 5 : ((N == 16) ? 4 : 3);
  // bit-reverse permute (indices fold to constants after unroll)
  #pragma unroll
  for (int i = 0; i < N; ++i) {
    int j = 0;
    #pragma unroll
    for (int bn = 0; bn < LOG; ++bn) j |= ((i >> bn) & 1) << (LOG - 1 - bn);
    if (j > i) { float2 t = a[i]; a[i] = a[j]; a[j] = t; }
  }
  #pragma unroll
  for (int s = 1; s <= LOG; ++s) {
    const int half  = 1 << (s - 1);
    const int tstep = 32 >> s;          // index step into the 32-entry table
    #pragma unroll
    for (int i = 0; i < N; i += (1 << s)) {
      #pragma unroll
      for (int k = 0; k < half; ++k) {
        const int   ti = k * tstep;
        const float wr = C32T[ti];
        const float wi = INV ? S32T[ti] : -S32T[ti];
        const float2 u = a[i + k];
        const float2 v = a[i + k + half];
        const float tr = v.x * wr - v.y * wi;
        const float tq = v.x * wi + v.y * wr;
        a[i + k]        = make_float2(u.x + tr, u.y + tq);
        a[i + k + half] = make_float2(u.x - tr, u.y - tq);
      }
    }
  }
}

template<int N, bool INV>
__device__ __forceinline__ void fft_row(float* re, float* im, int row, int LD) {
  float2 a[N];
  #pragma unroll
  for (int i = 0; i < N; ++i) a[i] = make_float2(re[row * LD + i], im[row * LD + i]);
  fft1d<N, INV>(a);
  #pragma unroll
  for (int i = 0; i < N; ++i) { re[row * LD + i] = a[i].x; im[row * LD + i] = a[i].y; }
}

template<int N, bool INV>
__device__ __forceinline__ void fft_col(float* re, float* im, int col, int LD) {
  float2 a[N];
  #pragma unroll
  for (int i = 0; i < N; ++i) a[i] = make_float2(re[i * LD + col], im[i * LD + col]);
  fft1d<N, INV>(a);
  #pragma unroll
  for (int i = 0; i < N; ++i) { re[i * LD + col] = a[i].x; im[i * LD + col] = a[i].y; }
}

// ---------------------------------------------------------------------------
// Kernel 1: per (b,c): xf, s0, u0/u0f (-> ws), s1a, u1 path -> s1b
// grid = B*3 = 192, block = 256
// ---------------------------------------------------------------------------
__global__ __launch_bounds__(256) void k_scatter1(
    const float* __restrict__ x, const float* __restrict__ psi0,
    const float* __restrict__ psi1, const float* __restrict__ phi,
    float* __restrict__ u0f_g, float* __restrict__ feat)
{
  __shared__ float Xr[1056], Xi[1056], Ph[1056];   // 32x33 (xf, phi)
  __shared__ float Ar[8448], Ai[8448];             // 8 x 32x33 (u0 planes)
  __shared__ float Br[2176], Bi[2176];             // 8 x 16x17 (u1 planes)
  __shared__ float Sr[648],  Si[648];              // 9 x 8x9   (8x8 stage)
  __shared__ float P1[272];                        // 16x17 (phi at res 1)
  const int tid = threadIdx.x;
  const int bc  = blockIdx.x;                      // b*3 + c
  const float* xp = x + bc * 1024;

  for (int e = tid; e < 1024; e += 256) {
    const int r = e >> 5, c = e & 31;
    Xr[r * 33 + c] = xp[e];
    Xi[r * 33 + c] = 0.0f;
    Ph[r * 33 + c] = phi[e];
  }
  { // phi1[u,v] = mean of 2x2 aliases of phi
    const int u = tid >> 4, v = tid & 15;
    P1[u * 17 + v] = 0.25f * (phi[u * 32 + v] + phi[u * 32 + v + 16] +
                              phi[(u + 16) * 32 + v] + phi[(u + 16) * 32 + v + 16]);
  }
  __syncthreads();

  // xf = fft2(x)
  if (tid < 32) fft_row<32, false>(Xr, Xi, tid, 33);
  __syncthreads();
  if (tid < 32) fft_col<32, false>(Xr, Xi, tid, 33);
  __syncthreads();

  // A[p] = xf * psi0[p]
  for (int e = tid; e < 8192; e += 256) {
    const int p = e >> 10, rc = e & 1023, r = rc >> 5, c = rc & 31;
    const float ps = psi0[e];
    const int o = p * 1056 + r * 33 + c;
    Ar[o] = Xr[r * 33 + c] * ps;
    Ai[o] = Xi[r * 33 + c] * ps;
  }
  __syncthreads();
  // ifft2 rows (8 planes x 32 rows = 256 threads)
  { const int p = tid >> 5, r = tid & 31; fft_row<32, true>(Ar + p * 1056, Ai + p * 1056, r, 33); }
  __syncthreads();
  // cols: inverse, |.|/1024, forward  (fuses u0 = abs(ifft2) and start of fft2(u0))
  {
    const int p = tid >> 5, col = tid & 31;
    float* re = Ar + p * 1056; float* im = Ai + p * 1056;
    float2 a[32];
    #pragma unroll
    for (int i = 0; i < 32; ++i) a[i] = make_float2(re[i * 33 + col], im[i * 33 + col]);
    fft1d<32, true>(a);
    #pragma unroll
    for (int i = 0; i < 32; ++i) {
      const float m = sqrtf(a[i].x * a[i].x + a[i].y * a[i].y) * (1.0f / 1024.0f);
      a[i] = make_float2(m, 0.0f);
    }
    fft1d<32, false>(a);
    #pragma unroll
    for (int i = 0; i < 32; ++i) { re[i * 33 + col] = a[i].x; im[i * 33 + col] = a[i].y; }
  }
  __syncthreads();
  // rows forward -> u0f
  { const int p = tid >> 5, r = tid & 31; fft_row<32, false>(Ar + p * 1056, Ai + p * 1056, r, 33); }
  __syncthreads();

  // store u0f to global for kernel 2 (coalesced float2)
  {
    float2* up = reinterpret_cast<float2*>(u0f_g) + (size_t)bc * 8192;
    for (int e = tid; e < 8192; e += 256) {
      const int p = e >> 10, rc = e & 1023, r = rc >> 5, c = rc & 31;
      up[e] = make_float2(Ar[p * 1056 + r * 33 + c], Ai[p * 1056 + r * 33 + c]);
    }
  }
  // s0 (p==8, source xf) and s1a (p=0..7, source u0f): Asub = mean_{4x4 alias}(src*phi)
  for (int e = tid; e < 576; e += 256) {
    const int p = e >> 6, u = (e >> 3) & 7, v = e & 7;
    float sr = 0.f, si = 0.f;
    #pragma unroll
    for (int i2 = 0; i2 < 4; ++i2)
      #pragma unroll
      for (int j2 = 0; j2 < 4; ++j2) {
        const int r = u + 8 * i2, c = v + 8 * j2;
        const float ph = Ph[r * 33 + c];
        float vr, vi;
        if (p == 8) { vr = Xr[r * 33 + c]; vi = Xi[r * 33 + c]; }
        else        { vr = Ar[p * 1056 + r * 33 + c]; vi = Ai[p * 1056 + r * 33 + c]; }
        sr += vr * ph; si += vi * ph;
      }
    Sr[p * 72 + u * 9 + v] = sr * 0.0625f;
    Si[p * 72 + u * 9 + v] = si * 0.0625f;
  }
  __syncthreads();
  if (tid < 72) { const int p = tid >> 3, r = tid & 7; fft_row<8, true>(Sr + p * 72, Si + p * 72, r, 9); }
  __syncthreads();
  if (tid < 72) {
    const int p = tid >> 3, col = tid & 7;
    float2 a[8];
    #pragma unroll
    for (int i = 0; i < 8; ++i) a[i] = make_float2(Sr[p * 72 + i * 9 + col], Si[p * 72 + i * 9 + col]);
    fft1d<8, true>(a);
    const int ch = (p == 8) ? 0 : (1 + p);
    float* fo = feat + ((size_t)bc * 81 + ch) * 64;
    #pragma unroll
    for (int i = 0; i < 8; ++i) fo[i * 8 + col] = a[i].x * (1.0f / 64.0f);
  }
  // u1 path: B[p] = sub(xf * psi1[p], 2)   (16x16)
  for (int e = tid; e < 2048; e += 256) {
    const int p = e >> 8, u = (e >> 4) & 15, v = e & 15;
    float sr = 0.f, si = 0.f;
    #pragma unroll
    for (int i2 = 0; i2 < 2; ++i2)
      #pragma unroll
      for (int j2 = 0; j2 < 2; ++j2) {
        const int r = u + 16 * i2, c = v + 16 * j2;
        const float ps = psi1[p * 1024 + r * 32 + c];
        sr += Xr[r * 33 + c] * ps; si += Xi[r * 33 + c] * ps;
      }
    Br[p * 272 + u * 17 + v] = 0.25f * sr;
    Bi[p * 272 + u * 17 + v] = 0.25f * si;
  }
  __syncthreads();
  if (tid < 128) { const int p = tid >> 4, r = tid & 15; fft_row<16, true>(Br + p * 272, Bi + p * 272, r, 17); }
  __syncthreads();
  if (tid < 128) { // cols: inverse, |.|/256, forward
    const int p = tid >> 4, col = tid & 15;
    float* re = Br + p * 272; float* im = Bi + p * 272;
    float2 a[16];
    #pragma unroll
    for (int i = 0; i < 16; ++i) a[i] = make_float2(re[i * 17 + col], im[i * 17 + col]);
    fft1d<16, true>(a);
    #pragma unroll
    for (int i = 0; i < 16; ++i) {
      const float m = sqrtf(a[i].x * a[i].x + a[i].y * a[i].y) * (1.0f / 256.0f);
      a[i] = make_float2(m, 0.0f);
    }
    fft1d<16, false>(a);
    #pragma unroll
    for (int i = 0; i < 16; ++i) { re[i * 17 + col] = a[i].x; im[i * 17 + col] = a[i].y; }
  }
  __syncthreads();
  if (tid < 128) { const int p = tid >> 4, r = tid & 15; fft_row<16, false>(Br + p * 272, Bi + p * 272, r, 17); }
  __syncthreads();
  // Z8 = sub(u1f * phi1, 2)
  for (int e = tid; e < 512; e += 256) {
    const int p = e >> 6, u = (e >> 3) & 7, v = e & 7;
    float sr = 0.f, si = 0.f;
    #pragma unroll
    for (int i2 = 0; i2 < 2; ++i2)
      #pragma unroll
      for (int j2 = 0; j2 < 2; ++j2) {
        const int r = u + 8 * i2, c = v + 8 * j2;
        const float ph = P1[r * 17 + c];
        sr += Br[p * 272 + r * 17 + c] * ph;
        si += Bi[p * 272 + r * 17 + c] * ph;
      }
    Sr[p * 72 + u * 9 + v] = 0.25f * sr;
    Si[p * 72 + u * 9 + v] = 0.25f * si;
  }
  __syncthreads();
  if (tid < 64) { const int p = tid >> 3, r = tid & 7; fft_row<8, true>(Sr + p * 72, Si + p * 72, r, 9); }
  __syncthreads();
  if (tid < 64) {
    const int p = tid >> 3, col = tid & 7;
    float2 a[8];
    #pragma unroll
    for (int i = 0; i < 8; ++i) a[i] = make_float2(Sr[p * 72 + i * 9 + col], Si[p * 72 + i * 9 + col]);
    fft1d<8, true>(a);
    float* fo = feat + ((size_t)bc * 81 + 9 + p) * 64;
    #pragma unroll
    for (int i = 0; i < 8; ++i) fo[i * 8 + col] = a[i].x * (1.0f / 64.0f);
  }
}

// ---------------------------------------------------------------------------
// Kernel 2: order-2 per (b,c,theta1): 8 theta2 planes -> s2
// grid = B*3*8 = 1536, block = 128
// ---------------------------------------------------------------------------
__global__ __launch_bounds__(128) void k_scatter2(
    const float* __restrict__ u0f_g, const float* __restrict__ psi1,
    const float* __restrict__ phi, float* __restrict__ feat)
{
  __shared__ float Ur[1056], Ui[1056];    // u0f plane 32x33
  __shared__ float Cr[2176], Ci[2176];    // 8 x 16x17
  __shared__ float Sr[576],  Si[576];     // 8 x 8x9
  __shared__ float P1[272];               // 16x17
  const int tid = threadIdx.x;
  const int blk = blockIdx.x;             // bc*8 + t1
  const float2* up = reinterpret_cast<const float2*>(u0f_g) + (size_t)blk * 1024;

  for (int e = tid; e < 1024; e += 128) {
    const float2 v = up[e];
    const int r = e >> 5, c = e & 31;
    Ur[r * 33 + c] = v.x; Ui[r * 33 + c] = v.y;
  }
  for (int e = tid; e < 256; e += 128) {
    const int u = e >> 4, v = e & 15;
    P1[u * 17 + v] = 0.25f * (phi[u * 32 + v] + phi[u * 32 + v + 16] +
                              phi[(u + 16) * 32 + v] + phi[(u + 16) * 32 + v + 16]);
  }
  __syncthreads();
  // C[p] = sub(u0f * psi1[p], 2)
  for (int e = tid; e < 2048; e += 128) {
    const int p = e >> 8, u = (e >> 4) & 15, v = e & 15;
    float sr = 0.f, si = 0.f;
    #pragma unroll
    for (int i2 = 0; i2 < 2; ++i2)
      #pragma unroll
      for (int j2 = 0; j2 < 2; ++j2) {
        const int r = u + 16 * i2, c = v + 16 * j2;
        const float ps = psi1[p * 1024 + r * 32 + c];
        sr += Ur[r * 33 + c] * ps; si += Ui[r * 33 + c] * ps;
      }
    Cr[p * 272 + u * 17 + v] = 0.25f * sr;
    Ci[p * 272 + u * 17 + v] = 0.25f * si;
  }
  __syncthreads();
  { const int p = tid >> 4, r = tid & 15; fft_row<16, true>(Cr + p * 272, Ci + p * 272, r, 17); }
  __syncthreads();
  { // cols: inverse, |.|/256, forward
    const int p = tid >> 4, col = tid & 15;
    float* re = Cr + p * 272; float* im = Ci + p * 272;
    float2 a[16];
    #pragma unroll
    for (int i = 0; i < 16; ++i) a[i] = make_float2(re[i * 17 + col], im[i * 17 + col]);
    fft1d<16, true>(a);
    #pragma unroll
    for (int i = 0; i < 16; ++i) {
      const float m = sqrtf(a[i].x * a[i].x + a[i].y * a[i].y) * (1.0f / 256.0f);
      a[i] = make_float2(m, 0.0f);
    }
    fft1d<16, false>(a);
    #pragma unroll
    for (int i = 0; i < 16; ++i) { re[i * 17 + col] = a[i].x; im[i * 17 + col] = a[i].y; }
  }
  __syncthreads();
  { const int p = tid >> 4, r = tid & 15; fft_row<16, false>(Cr + p * 272, Ci + p * 272, r, 17); }
  __syncthreads();
  // Z8 = sub(u2f * phi1, 2)
  for (int e = tid; e < 512; e += 128) {
    const int p = e >> 6, u = (e >> 3) & 7, v = e & 7;
    float sr = 0.f, si = 0.f;
    #pragma unroll
    for (int i2 = 0; i2 < 2; ++i2)
      #pragma unroll
      for (int j2 = 0; j2 < 2; ++j2) {
        const int r = u + 8 * i2, c = v + 8 * j2;
        const float ph = P1[r * 17 + c];
        sr += Cr[p * 272 + r * 17 + c] * ph;
        si += Ci[p * 272 + r * 17 + c] * ph;
      }
    Sr[p * 72 + u * 9 + v] = 0.25f * sr;
    Si[p * 72 + u * 9 + v] = 0.25f * si;
  }
  __syncthreads();
  if (tid < 64) { const int p = tid >> 3, r = tid & 7; fft_row<8, true>(Sr + p * 72, Si + p * 72, r, 9); }
  __syncthreads();
  if (tid < 64) {
    const int p = tid >> 3, col = tid & 7;
    float2 a[8];
    #pragma unroll
    for (int i = 0; i < 8; ++i) a[i] = make_float2(Sr[p * 72 + i * 9 + col], Si[p * 72 + i * 9 + col]);
    fft1d<8, true>(a);
    const int bc = blk >> 3, t1 = blk & 7;
    float* fo = feat + ((size_t)bc * 81 + 17 + t1 * 8 + p) * 64;
    #pragma unroll
    for (int i = 0; i < 8; ++i) fo[i * 8 + col] = a[i].x * (1.0f / 64.0f);
  }
}

// ---------------------------------------------------------------------------
// Kernel 3: GroupNorm(27 groups over 243ch x 8x8) + Linear(15552 -> 10)
// grid = B = 64, block = 256
// ---------------------------------------------------------------------------
__global__ __launch_bounds__(256) void k_gn_linear(
    const float* __restrict__ feat, const float* __restrict__ gamma,
    const float* __restrict__ beta, const float* __restrict__ W,
    const float* __restrict__ bias, float* __restrict__ out)
{
  __shared__ float F[15552];
  __shared__ float gmu[27], grs[27];
  __shared__ float red[40];
  const int tid = threadIdx.x, b = blockIdx.x;
  const float* fp = feat + (size_t)b * 15552;
  for (int e = tid; e < 15552; e += 256) F[e] = fp[e];
  __syncthreads();
  // two-pass group stats: 27 groups x 8 lanes
  if (tid < 216) {
    const int g = tid >> 3, l8 = tid & 7;
    float s = 0.f;
    for (int e = l8; e < 576; e += 8) s += F[g * 576 + e];
    #pragma unroll
    for (int off = 1; off < 8; off <<= 1) s += __shfl_down(s, off);
    if (l8 == 0) gmu[g] = s * (1.0f / 576.0f);
  }
  __syncthreads();
  if (tid < 216) {
    const int g = tid >> 3, l8 = tid & 7;
    const float mu = gmu[g];
    float ss = 0.f;
    for (int e = l8; e < 576; e += 8) { const float d = F[g * 576 + e] - mu; ss += d * d; }
    #pragma unroll
    for (int off = 1; off < 8; off <<= 1) ss += __shfl_down(ss, off);
    if (l8 == 0) grs[g] = rsqrtf(ss * (1.0f / 576.0f) + 1e-5f);
  }
  __syncthreads();
  for (int e = tid; e < 15552; e += 256) {
    const int ch = e >> 6, g = ch / 9;
    F[e] = (F[e] - gmu[g]) * grs[g] * gamma[ch] + beta[ch];
  }
  __syncthreads();
  float acc[10];
  #pragma unroll
  for (int k = 0; k < 10; ++k) acc[k] = 0.f;
  for (int e = tid; e < 15552; e += 256) {
    const float v = F[e];
    #pragma unroll
    for (int k = 0; k < 10; ++k) acc[k] = fmaf(v, W[k * 15552 + e], acc[k]);
  }
  #pragma unroll
  for (int k = 0; k < 10; ++k) {
    float v = acc[k];
    #pragma unroll
    for (int off = 32; off > 0; off >>= 1) v += __shfl_down(v, off);
    if ((tid & 63) == 0) red[(tid >> 6) * 10 + k] = v;
  }
  __syncthreads();
  if (tid < 10) {
    out[b * 10 + tid] = red[tid] + red[10 + tid] + red[20 + tid] + red[30 + tid] + bias[tid];
  }
}

// ---------------------------------------------------------------------------
extern "C" void kernel_launch(void* const* d_in, const int* in_sizes, int n_in,
                              void* d_out, int out_size, void* d_ws, size_t ws_size,
                              hipStream_t stream) {
  (void)in_sizes; (void)n_in; (void)out_size; (void)ws_size;
  const float* x     = (const float*)d_in[0];
  const float* psi0  = (const float*)d_in[1];
  const float* psi1  = (const float*)d_in[2];
  const float* phi   = (const float*)d_in[3];
  const float* gamma = (const float*)d_in[4];
  const float* beta  = (const float*)d_in[5];
  const float* W     = (const float*)d_in[6];
  const float* bias  = (const float*)d_in[7];
  float* out = (float*)d_out;

  float* u0f  = (float*)d_ws;                       // 192*8192 complex = 12.6 MB
  float* feat = u0f + (size_t)192 * 8192 * 2;       // 64*243*64 floats ~ 4 MB

  hipLaunchKernelGGL(k_scatter1, dim3(192),  dim3(256), 0, stream, x, psi0, psi1, phi, u0f, feat);
  hipLaunchKernelGGL(k_scatter2, dim3(1536), dim3(128), 0, stream, u0f, psi1, phi, feat);
  hipLaunchKernelGGL(k_gn_linear, dim3(64),  dim3(256), 0, stream, feat, gamma, beta, W, bias, out);
}